// Round 5
// baseline (891.762 us; speedup 1.0000x reference)
//
#include <hip/hip_runtime.h>

#define N_NODES 200000
#define DIM 64
#define BSHIFT 9                       // 512 rows per bucket
#define NB 391                         // ceil(200000 / 512)
#define NB_PAD 512
#define CHUNK 4096                     // edges per bucket_scatter block

__device__ __forceinline__ float bf2f(unsigned short u) {
    return __uint_as_float(((unsigned int)u) << 16);
}
__device__ __forceinline__ unsigned short f2bf(float f) {
    unsigned int u = __float_as_uint(f);
    u += 0x7FFFu + ((u >> 16) & 1u);   // round-to-nearest-even
    return (unsigned short)(u >> 16);
}

// ---- Pass A: bucket histogram (LDS-staged) ----
__global__ __launch_bounds__(256) void bucket_hist(const int* __restrict__ rows, int E,
                                                   int* __restrict__ bcnt) {
    __shared__ int h[NB_PAD];
    for (int i = threadIdx.x; i < NB_PAD; i += 256) h[i] = 0;
    __syncthreads();
    int stride = gridDim.x * blockDim.x;
    for (int e = blockIdx.x * blockDim.x + threadIdx.x; e < E; e += stride)
        atomicAdd(&h[rows[e] >> BSHIFT], 1);
    __syncthreads();
    for (int i = threadIdx.x; i < NB; i += 256)
        if (h[i]) atomicAdd(&bcnt[i], h[i]);
}

// ---- Pass B: parallel exclusive scan of bucket counts (one block, LDS) ----
__global__ __launch_bounds__(NB_PAD) void bucket_scan(const int* __restrict__ bcnt,
                                                      int* __restrict__ bbase,
                                                      int* __restrict__ bcur) {
    __shared__ int s[NB_PAD];
    int t = threadIdx.x;
    int mine = (t < NB) ? bcnt[t] : 0;
    s[t] = mine;
    __syncthreads();
    for (int off = 1; off < NB_PAD; off <<= 1) {
        int v = s[t] + ((t >= off) ? s[t - off] : 0);
        __syncthreads();
        s[t] = v;
        __syncthreads();
    }
    if (t < NB) {
        int excl = s[t] - mine;
        bbase[t] = excl;
        bcur[t] = excl;
        if (t == NB - 1) bbase[NB] = s[t];
    }
}

// ---- Pass C: chunked scatter into bucket-grouped tmp, LDS-staged coalesced writes ----
__global__ __launch_bounds__(256) void bucket_scatter(const int* __restrict__ rows,
                                                      const int* __restrict__ cols,
                                                      const float* __restrict__ vals, int E,
                                                      int* __restrict__ bcur,
                                                      int2* __restrict__ tmp) {
    __shared__ int h[NB_PAD];
    __shared__ int incl[NB_PAD];
    __shared__ int sbuf[NB_PAD];
    __shared__ int fix[NB_PAD];
    __shared__ int cur2[NB_PAD];
    __shared__ int2 stage[CHUNK];
    __shared__ unsigned short sbkt[CHUNK];
    const int base = blockIdx.x * CHUNK;
    const int count = min(CHUNK, E - base);
    const int t = threadIdx.x;

    for (int i = t; i < NB_PAD; i += 256) h[i] = 0;
    __syncthreads();
    for (int i = t; i < count; i += 256)
        atomicAdd(&h[rows[base + i] >> BSHIFT], 1);
    __syncthreads();
    for (int i = t; i < NB_PAD; i += 256) incl[i] = h[i];
    __syncthreads();
    for (int off = 1; off < NB_PAD; off <<= 1) {
        for (int i = t; i < NB_PAD; i += 256)
            sbuf[i] = incl[i] + ((i >= off) ? incl[i - off] : 0);
        __syncthreads();
        for (int i = t; i < NB_PAD; i += 256) incl[i] = sbuf[i];
        __syncthreads();
    }
    for (int i = t; i < NB; i += 256) {
        int excl = incl[i] - h[i];
        int g = h[i] ? atomicAdd(&bcur[i], h[i]) : 0;
        fix[i] = g - excl;
        cur2[i] = excl;
    }
    __syncthreads();
    for (int i = t; i < count; i += 256) {
        int r = rows[base + i];
        int b = r >> BSHIFT;
        int slot = atomicAdd(&cur2[b], 1);
        int key = ((r & ((1 << BSHIFT) - 1)) << 18) | cols[base + i];
        stage[slot] = make_int2(key, __float_as_int(vals[base + i]));
        sbkt[slot] = (unsigned short)b;
    }
    __syncthreads();
    for (int s = t; s < count; s += 256)
        tmp[s + fix[sbkt[s]]] = stage[s];
}

// ---- Pass D: per-bucket counting sort by row; emit cols_s (int) + vals_s (bf16) + row_start ----
__global__ __launch_bounds__(256) void bucket_sort(const int2* __restrict__ tmp,
                                                   const int* __restrict__ bbase,
                                                   int* __restrict__ cols_s,
                                                   unsigned short* __restrict__ vals_s,
                                                   int* __restrict__ row_start) {
    __shared__ int h[NB_PAD];
    __shared__ int sums[256];
    const int b = blockIdx.x;
    const int s0 = bbase[b], s1 = bbase[b + 1];
    const int t = threadIdx.x;
    h[t] = 0; h[t + 256] = 0;
    __syncthreads();
    for (int e = s0 + t; e < s1; e += 256)
        atomicAdd(&h[tmp[e].x >> 18], 1);
    __syncthreads();
    int a0 = h[2 * t], a1 = h[2 * t + 1];
    sums[t] = a0 + a1;
    __syncthreads();
    if (t == 0) {
        int run = 0;
        for (int i = 0; i < 256; i++) { int v = sums[i]; sums[i] = run; run += v; }
    }
    __syncthreads();
    int e0 = sums[t];
    h[2 * t] = e0;
    h[2 * t + 1] = e0 + a0;
    __syncthreads();
    int rbase = b << BSHIFT;
    for (int r = t; r < (1 << BSHIFT); r += 256) {
        int row = rbase + r;
        if (row < N_NODES) row_start[row] = s0 + h[r];
    }
    if (b == NB - 1 && t == 0) row_start[N_NODES] = s1;
    __syncthreads();
    for (int e = s0 + t; e < s1; e += 256) {
        int2 kv = tmp[e];
        int r = kv.x >> 18;
        int rank = atomicAdd(&h[r], 1);
        int pos = s0 + rank;
        cols_s[pos] = kv.x & 0x3FFFF;
        vals_s[pos] = f2bf(__int_as_float(kv.y));
    }
}

// ---- fp32 -> bf16 convert (embeds -> xb0) ----
__global__ __launch_bounds__(256) void convert_kernel(const float* __restrict__ src,
                                                      unsigned short* __restrict__ dst, int n4) {
    int i = blockIdx.x * blockDim.x + threadIdx.x;
    if (i >= n4) return;
    float4 v = *(const float4*)(src + i * 4);
    ushort4 o;
    o.x = f2bf(v.x); o.y = f2bf(v.y); o.z = f2bf(v.z); o.w = f2bf(v.w);
    *(ushort4*)(dst + i * 4) = o;
}

// ---- core gather-accumulate over one row segment ----
__device__ __forceinline__ float4 row_gather(const int* __restrict__ cols_s,
                                             const unsigned short* __restrict__ vals_s,
                                             const unsigned short* __restrict__ xb,
                                             int e, int eend, int j) {
    float4 a = make_float4(0.f, 0.f, 0.f, 0.f);
    for (; e + 4 <= eend; e += 4) {
        int c0 = cols_s[e], c1 = cols_s[e + 1], c2 = cols_s[e + 2], c3 = cols_s[e + 3];
        float v0 = bf2f(vals_s[e]),     v1 = bf2f(vals_s[e + 1]);
        float v2 = bf2f(vals_s[e + 2]), v3 = bf2f(vals_s[e + 3]);
        ushort4 u0 = *(const ushort4*)(xb + (c0 << 6) + j);
        ushort4 u1 = *(const ushort4*)(xb + (c1 << 6) + j);
        ushort4 u2 = *(const ushort4*)(xb + (c2 << 6) + j);
        ushort4 u3 = *(const ushort4*)(xb + (c3 << 6) + j);
        a.x = fmaf(v0, bf2f(u0.x), a.x); a.y = fmaf(v0, bf2f(u0.y), a.y);
        a.z = fmaf(v0, bf2f(u0.z), a.z); a.w = fmaf(v0, bf2f(u0.w), a.w);
        a.x = fmaf(v1, bf2f(u1.x), a.x); a.y = fmaf(v1, bf2f(u1.y), a.y);
        a.z = fmaf(v1, bf2f(u1.z), a.z); a.w = fmaf(v1, bf2f(u1.w), a.w);
        a.x = fmaf(v2, bf2f(u2.x), a.x); a.y = fmaf(v2, bf2f(u2.y), a.y);
        a.z = fmaf(v2, bf2f(u2.z), a.z); a.w = fmaf(v2, bf2f(u2.w), a.w);
        a.x = fmaf(v3, bf2f(u3.x), a.x); a.y = fmaf(v3, bf2f(u3.y), a.y);
        a.z = fmaf(v3, bf2f(u3.z), a.z); a.w = fmaf(v3, bf2f(u3.w), a.w);
    }
    for (; e < eend; ++e) {
        int c = cols_s[e];
        float v = bf2f(vals_s[e]);
        ushort4 u = *(const ushort4*)(xb + (c << 6) + j);
        a.x = fmaf(v, bf2f(u.x), a.x);
        a.y = fmaf(v, bf2f(u.y), a.y);
        a.z = fmaf(v, bf2f(u.z), a.z);
        a.w = fmaf(v, bf2f(u.w), a.w);
    }
    return a;
}

// ---- layers 1..3: y = A * xb (bf16 in, bf16 out, no acc traffic) ----
__global__ __launch_bounds__(256) void spmm_prop(const int* __restrict__ cols_s,
                                                 const unsigned short* __restrict__ vals_s,
                                                 const int* __restrict__ row_start,
                                                 const unsigned short* __restrict__ xb,
                                                 unsigned short* __restrict__ y) {
    int gid = blockIdx.x * blockDim.x + threadIdx.x;
    int r = gid >> 4;
    if (r >= N_NODES) return;
    int j = (gid & 15) << 2;
    float4 a = row_gather(cols_s, vals_s, xb, row_start[r], row_start[r + 1], j);
    ushort4 yo; yo.x = f2bf(a.x); yo.y = f2bf(a.y); yo.z = f2bf(a.z); yo.w = f2bf(a.w);
    *(ushort4*)(y + (r << 6) + j) = yo;
}

// ---- layer 4 + fused mean: acc = 0.2*(embeds + y1 + y2 + y3 + A*y3) ----
__global__ __launch_bounds__(256) void spmm_final(const int* __restrict__ cols_s,
                                                  const unsigned short* __restrict__ vals_s,
                                                  const int* __restrict__ row_start,
                                                  const unsigned short* __restrict__ y3,
                                                  const float* __restrict__ embeds,
                                                  const unsigned short* __restrict__ y1,
                                                  const unsigned short* __restrict__ y2,
                                                  float* __restrict__ acc) {
    int gid = blockIdx.x * blockDim.x + threadIdx.x;
    int r = gid >> 4;
    if (r >= N_NODES) return;
    int j = (gid & 15) << 2;
    float4 a = row_gather(cols_s, vals_s, y3, row_start[r], row_start[r + 1], j);
    int o = (r << 6) + j;
    const float4 e0 = *(const float4*)(embeds + o);
    ushort4 u1 = *(const ushort4*)(y1 + o);
    ushort4 u2 = *(const ushort4*)(y2 + o);
    ushort4 u3 = *(const ushort4*)(y3 + o);
    const float s = 0.2f;
    float4 out;
    out.x = (e0.x + bf2f(u1.x) + bf2f(u2.x) + bf2f(u3.x) + a.x) * s;
    out.y = (e0.y + bf2f(u1.y) + bf2f(u2.y) + bf2f(u3.y) + a.y) * s;
    out.z = (e0.z + bf2f(u1.z) + bf2f(u2.z) + bf2f(u3.z) + a.z) * s;
    out.w = (e0.w + bf2f(u1.w) + bf2f(u2.w) + bf2f(u3.w) + a.w) * s;
    *(float4*)(acc + o) = out;
}

extern "C" void kernel_launch(void* const* d_in, const int* in_sizes, int n_in,
                              void* d_out, int out_size, void* d_ws, size_t ws_size,
                              hipStream_t stream) {
    const float* embeds = (const float*)d_in[0];
    const int*   rows   = (const int*)d_in[1];
    const int*   cols   = (const int*)d_in[2];
    const float* vals   = (const float*)d_in[3];
    float* acc = (float*)d_out;
    const int E = in_sizes[1];

    // workspace carve-out (~142 MB); y2/y3 alias tmp (tmp dead after bucket_sort)
    char* ws = (char*)d_ws;
    size_t off = 0;
    auto alloc = [&](size_t bytes) -> char* {
        char* p = ws + off;
        off = (off + bytes + 255) & ~(size_t)255;
        return p;
    };
    int*   bcnt      = (int*)alloc((size_t)NB * 4);
    int*   bbase     = (int*)alloc((size_t)(NB + 1) * 4);
    int*   bcur      = (int*)alloc((size_t)NB * 4);
    int*   row_start = (int*)alloc((size_t)(N_NODES + 1) * 4);
    int*   cols_s    = (int*)alloc((size_t)E * 4);                            // 25.6 MB
    unsigned short* vals_s = (unsigned short*)alloc((size_t)E * 2);           // 12.8 MB
    unsigned short* xb0 = (unsigned short*)alloc((size_t)N_NODES * DIM * 2);  // 25.6 MB
    unsigned short* y1  = (unsigned short*)alloc((size_t)N_NODES * DIM * 2);  // 25.6 MB
    int2*  tmp       = (int2*)alloc((size_t)E * 8);                           // 51.2 MB
    unsigned short* y2 = (unsigned short*)tmp;
    unsigned short* y3 = (unsigned short*)tmp + (size_t)N_NODES * DIM;

    hipMemsetAsync(bcnt, 0, (size_t)NB * 4, stream);

    bucket_hist<<<512, 256, 0, stream>>>(rows, E, bcnt);
    bucket_scan<<<1, NB_PAD, 0, stream>>>(bcnt, bbase, bcur);
    bucket_scatter<<<(E + CHUNK - 1) / CHUNK, 256, 0, stream>>>(rows, cols, vals, E, bcur, tmp);
    bucket_sort<<<NB, 256, 0, stream>>>(tmp, bbase, cols_s, vals_s, row_start);

    int n4 = N_NODES * DIM / 4;
    convert_kernel<<<(n4 + 255) / 256, 256, 0, stream>>>(embeds, xb0, n4);

    int sb = (N_NODES * 16 + 255) / 256;   // 16 threads per row
    spmm_prop<<<sb, 256, 0, stream>>>(cols_s, vals_s, row_start, xb0, y1);   // y1 = A x0
    spmm_prop<<<sb, 256, 0, stream>>>(cols_s, vals_s, row_start, y1, y2);    // y2 = A y1
    spmm_prop<<<sb, 256, 0, stream>>>(cols_s, vals_s, row_start, y2, y3);    // y3 = A y2
    spmm_final<<<sb, 256, 0, stream>>>(cols_s, vals_s, row_start, y3, embeds, y1, y2, acc);
}